// Round 9
// baseline (272.466 us; speedup 1.0000x reference)
//
#include <hip/hip_runtime.h>
#include <hip/hip_bf16.h>

typedef __attribute__((ext_vector_type(8))) __bf16 bf16x8;
typedef __attribute__((ext_vector_type(4))) float floatx4;

#define N_NODES   20000
#define N_EDGES   320000
#define IN_DIM    128
#define HID       64
#define HEADS     4
#define NUM_GRAPHS 128
#define N_CLASSES 10

__device__ inline float cvt_load(const void* p, int i, int isb) {
    return isb ? __bfloat162float(((const __hip_bfloat16*)p)[i]) : ((const float*)p)[i];
}

__device__ inline unsigned short bf16bits(float v) {
    return __builtin_bit_cast(unsigned short, __float2bfloat16(v));
}

__device__ inline unsigned pack2(float a, float b) {
    return (unsigned)bf16bits(a) | ((unsigned)bf16bits(b) << 16);
}

__device__ inline floatx4 unpack4(uint2 u) {
    floatx4 f;
    f.x = __uint_as_float(u.x << 16);
    f.y = __uint_as_float(u.x & 0xffff0000u);
    f.z = __uint_as_float(u.y << 16);
    f.w = __uint_as_float(u.y & 0xffff0000u);
    return f;
}

// ---------- init: block 0 = dtype detect; remaining blocks zero cnt ----------
__global__ void init_kernel(const unsigned int* hw, int nwords, int* flag,
                            unsigned int* cnt, int n1) {
    int b = blockIdx.x;
    if (b == 0) {
        __shared__ int s_bad;
        if (threadIdx.x == 0) s_bad = 0;
        __syncthreads();
        int bad = 0;
        for (int i = threadIdx.x; i < nwords; i += 256) {
            float v = __uint_as_float(hw[i]);
            if (!(fabsf(v) <= 1e20f)) bad = 1;
        }
        if (bad) atomicOr(&s_bad, 1);
        __syncthreads();
        if (threadIdx.x == 0) *flag = s_bad;
    } else {
        int i = (b - 1) * 256 + threadIdx.x;
        if (i < n1) cnt[i] = 0u;
    }
}

// ---------- fused prep: convW [0,195) | convH-if-f32 [195,835) | count [835,2085) ----------
__global__ void prep_kernel(const void* W1, const void* W2, const void* Wc, const void* bc,
                            unsigned short* W1t, unsigned short* W2t, float* Wcf, float* bcf,
                            const void* h, unsigned short* hb,
                            const int* __restrict__ dst, int* __restrict__ cnt,
                            const int* flag) {
    int b = blockIdx.x;
    const int n1 = IN_DIM * HID * HEADS;        // 32768
    const int n2 = HID * HEADS * HID;           // 16384
    const int n3 = HID * N_CLASSES;             // 640
    const int n4 = N_CLASSES;                   // 10
    if (b < 195) {
        int i = b * 256 + threadIdx.x;
        int isb = *flag;
        if (i < n1) {
            int k = i >> 8, n = i & 255;            // W1[k][n]
            W1t[n * 128 + k] = bf16bits(cvt_load(W1, i, isb));
        } else if (i < n1 + n2) {
            int j = i - n1;
            int k = j >> 6, n = j & 63;             // W2[k][n]
            W2t[n * 256 + k] = bf16bits(cvt_load(W2, j, isb));
        } else if (i < n1 + n2 + n3) {
            int j = i - n1 - n2;
            Wcf[j] = cvt_load(Wc, j, isb);
        } else if (i < n1 + n2 + n3 + n4) {
            int j = i - n1 - n2 - n3;
            bcf[j] = cvt_load(bc, j, isb);
        }
    } else if (b < 195 + 640) {
        int isb = *flag;
        if (!isb) {
            int base = (b - 195) * 4096;
            for (int t = 0; t < 16; ++t) {
                int i = base + t * 256 + threadIdx.x;
                if (i < N_NODES * IN_DIM) hb[i] = bf16bits(cvt_load(h, i, 0));
            }
        }
    } else {
        int e = (b - 835) * 256 + threadIdx.x;
        if (e < N_EDGES) atomicAdd(&cnt[dst[e]], 1);
    }
}

// ---------- scan (R8-proven): 1024 threads, 20 elem/thread serial + one block scan ----------
__global__ void scan_kernel(const int* __restrict__ cnt, int* __restrict__ off,
                            int* __restrict__ off_work, int n) {
    const int CH = 20;
    __shared__ int wsum[16];
    int tid  = threadIdx.x;
    int lane = tid & 63;
    int w    = tid >> 6;
    int base = tid * CH;
    int local[CH];
    int s = 0;
#pragma unroll
    for (int i = 0; i < CH; ++i) {
        int idx = base + i;
        int v = (idx < n) ? cnt[idx] : 0;
        local[i] = s;
        s += v;
    }
    int x = s;
#pragma unroll
    for (int sh = 1; sh < 64; sh <<= 1) {
        int t = __shfl_up(x, sh);
        if (lane >= sh) x += t;
    }
    if (lane == 63) wsum[w] = x;
    __syncthreads();
    if (w == 0 && lane < 16) {
        int y = wsum[lane];
#pragma unroll
        for (int sh = 1; sh < 16; sh <<= 1) {
            int t = __shfl_up(y, sh);
            if (lane >= sh) y += t;
        }
        wsum[lane] = y;
    }
    __syncthreads();
    int thread_off = ((w > 0) ? wsum[w - 1] : 0) + (x - s);
#pragma unroll
    for (int i = 0; i < CH; ++i) {
        int idx = base + i;
        if (idx < n) {
            int e = thread_off + local[i];
            off[idx] = e;
            off_work[idx] = e;
        }
    }
    if (tid == 1023) off[n] = thread_off + s;
}

// ---------- fused fill [0,1250) + gemm1 [1250,1563): independent phases ----------
__global__ __launch_bounds__(256) void fillgemm1_kernel(
        const int* __restrict__ src, const int* __restrict__ dst,
        int* __restrict__ off_work, int* __restrict__ csr_src,
        const void* __restrict__ h_any, const unsigned short* __restrict__ h_b,
        const unsigned short* __restrict__ Bt, unsigned short* __restrict__ C,
        const int* flag) {
    int b = blockIdx.x;
    if (b < 1250) {
        int e = b * 256 + threadIdx.x;
        if (e < N_EDGES) {
            int d = dst[e];
            int pos = atomicAdd(&off_work[d], 1);
            csr_src[pos] = src[e];
        }
        return;
    }
    // ---- gemm1: ft1[M,256] = A[M,128] @ W1 ----
    const int M = N_NODES;
    const unsigned short* A = (*flag) ? (const unsigned short*)h_any : h_b;
    int wave = threadIdx.x >> 6;
    int lane = threadIdx.x & 63;
    int q = lane >> 4, r = lane & 15;
    int m0 = (b - 1250) * 64;
    int n0 = wave * 64;
    floatx4 acc[4][4] = {};
    bf16x8 bfrag[4][4];
#pragma unroll
    for (int ni = 0; ni < 4; ++ni)
#pragma unroll
        for (int kk = 0; kk < 4; ++kk)
            bfrag[ni][kk] = *(const bf16x8*)(Bt + (n0 + ni * 16 + r) * 128 + kk * 32 + q * 8);
#pragma unroll
    for (int kk = 0; kk < 4; ++kk) {
        bf16x8 afrag[4];
#pragma unroll
        for (int mi = 0; mi < 4; ++mi) {
            int row = m0 + mi * 16 + r;
            bf16x8 a = {};
            if (row < M) a = *(const bf16x8*)(A + row * 128 + kk * 32 + q * 8);
            afrag[mi] = a;
        }
#pragma unroll
        for (int mi = 0; mi < 4; ++mi)
#pragma unroll
            for (int ni = 0; ni < 4; ++ni)
                acc[mi][ni] = __builtin_amdgcn_mfma_f32_16x16x32_bf16(afrag[mi], bfrag[ni][kk], acc[mi][ni], 0, 0, 0);
    }
#pragma unroll
    for (int mi = 0; mi < 4; ++mi)
#pragma unroll
        for (int rr = 0; rr < 4; ++rr) {
            int row = m0 + mi * 16 + q * 4 + rr;
            if (row < M) {
#pragma unroll
                for (int ni = 0; ni < 4; ++ni)
                    C[row * 256 + n0 + ni * 16 + r] = bf16bits(acc[mi][ni][rr]);
            }
        }
}

// ---------- attention H=4 + fused layer-2 GEMM row: wave = dst ----------
// Main loop (R8-proven, unroll-4) -> x1 row in registers -> LDS -> ft2 row = x1 @ W2.
__global__ __launch_bounds__(256) void attn_h4_kernel(const unsigned short* __restrict__ ft,
                                                      const int* __restrict__ off,
                                                      const int* __restrict__ csr,
                                                      const unsigned short* __restrict__ W2t,
                                                      unsigned short* __restrict__ ft2) {
    __shared__ float xs[4][256];
    int wv   = threadIdx.x >> 6;
    int dstv = blockIdx.x * 4 + wv;
    int lane = threadIdx.x & 63;
    floatx4 hd = unpack4(*(const uint2*)(ft + dstv * 256 + lane * 4));
    int beg = off[dstv], end = off[dstv + 1];
    float l = 0.f;
    floatx4 acc = {0.f, 0.f, 0.f, 0.f};
    int e = beg;
    for (; e + 4 <= end; e += 4) {
        int sn0 = csr[e], sn1 = csr[e + 1], sn2 = csr[e + 2], sn3 = csr[e + 3];
        uint2 r0 = *(const uint2*)(ft + sn0 * 256 + lane * 4);
        uint2 r1 = *(const uint2*)(ft + sn1 * 256 + lane * 4);
        uint2 r2 = *(const uint2*)(ft + sn2 * 256 + lane * 4);
        uint2 r3 = *(const uint2*)(ft + sn3 * 256 + lane * 4);
        floatx4 h0 = unpack4(r0), h1 = unpack4(r1), h2 = unpack4(r2), h3 = unpack4(r3);
        float p0 = h0.x * hd.x + h0.y * hd.y + h0.z * hd.z + h0.w * hd.w;
        float p1 = h1.x * hd.x + h1.y * hd.y + h1.z * hd.z + h1.w * hd.w;
        float p2 = h2.x * hd.x + h2.y * hd.y + h2.z * hd.z + h2.w * hd.w;
        float p3 = h3.x * hd.x + h3.y * hd.y + h3.z * hd.z + h3.w * hd.w;
        p0 += __shfl_xor(p0, 1); p1 += __shfl_xor(p1, 1); p2 += __shfl_xor(p2, 1); p3 += __shfl_xor(p3, 1);
        p0 += __shfl_xor(p0, 2); p1 += __shfl_xor(p1, 2); p2 += __shfl_xor(p2, 2); p3 += __shfl_xor(p3, 2);
        p0 += __shfl_xor(p0, 4); p1 += __shfl_xor(p1, 4); p2 += __shfl_xor(p2, 4); p3 += __shfl_xor(p3, 4);
        p0 += __shfl_xor(p0, 8); p1 += __shfl_xor(p1, 8); p2 += __shfl_xor(p2, 8); p3 += __shfl_xor(p3, 8);
        float w0 = __expf(p0 * 0.125f);
        float w1 = __expf(p1 * 0.125f);
        float w2 = __expf(p2 * 0.125f);
        float w3 = __expf(p3 * 0.125f);
        l += (w0 + w1) + (w2 + w3);
        acc.x += w0 * h0.x + w1 * h1.x + w2 * h2.x + w3 * h3.x;
        acc.y += w0 * h0.y + w1 * h1.y + w2 * h2.y + w3 * h3.y;
        acc.z += w0 * h0.z + w1 * h1.z + w2 * h2.z + w3 * h3.z;
        acc.w += w0 * h0.w + w1 * h1.w + w2 * h2.w + w3 * h3.w;
    }
    for (; e < end; ++e) {
        int sn = csr[e];
        floatx4 hs = unpack4(*(const uint2*)(ft + sn * 256 + lane * 4));
        float p = hs.x * hd.x + hs.y * hd.y + hs.z * hd.z + hs.w * hd.w;
        p += __shfl_xor(p, 1); p += __shfl_xor(p, 2);
        p += __shfl_xor(p, 4); p += __shfl_xor(p, 8);
        float wgt = __expf(p * 0.125f);
        l += wgt;
        acc.x += wgt * hs.x; acc.y += wgt * hs.y;
        acc.z += wgt * hs.z; acc.w += wgt * hs.w;
    }
    float inv = (l > 0.f) ? 1.f / l : 0.f;
    floatx4 xv = {fmaxf(acc.x * inv, 0.f), fmaxf(acc.y * inv, 0.f),
                  fmaxf(acc.z * inv, 0.f), fmaxf(acc.w * inv, 0.f)};
    *(floatx4*)&xs[wv][lane * 4] = xv;
    __syncthreads();
    // ft2[dstv][lane] = sum_k xs[k] * W2[k][lane]  (W2t[lane][k], bf16x8 loads)
    const unsigned short* wrow = W2t + lane * 256;
    const float* xp = xs[wv];
    float o = 0.f;
#pragma unroll 4
    for (int k8 = 0; k8 < 32; ++k8) {
        uint4 wb = *(const uint4*)(wrow + k8 * 8);
        floatx4 wa = unpack4(make_uint2(wb.x, wb.y));
        floatx4 wc = unpack4(make_uint2(wb.z, wb.w));
        const float* xq = xp + k8 * 8;
        o += xq[0] * wa.x + xq[1] * wa.y + xq[2] * wa.z + xq[3] * wa.w
           + xq[4] * wc.x + xq[5] * wc.y + xq[6] * wc.z + xq[7] * wc.w;
    }
    ft2[dstv * 64 + lane] = bf16bits(o);
}

// ---------- attention H=1 (R8-proven): wave = dst, 4 edge-groups x 16 lanes, unroll-2 ----------
__global__ __launch_bounds__(256) void attn_h1_kernel(const unsigned short* __restrict__ ft,
                                                      const int* __restrict__ off,
                                                      const int* __restrict__ csr,
                                                      float* __restrict__ out) {
    int dstv = blockIdx.x * 4 + (threadIdx.x >> 6);
    int lane = threadIdx.x & 63;
    int g = lane >> 4, s = lane & 15;
    int hbase = s * 4;
    floatx4 hd = unpack4(*(const uint2*)(ft + dstv * 64 + hbase));
    int beg = off[dstv], end = off[dstv + 1];
    float l = 0.f;
    floatx4 acc = {0.f, 0.f, 0.f, 0.f};
    int e0 = beg;
    for (; e0 + 8 <= end; e0 += 8) {
        int ea = e0 + g, eb = e0 + 4 + g;
        int sa = csr[ea], sb = csr[eb];
        uint2 ra = *(const uint2*)(ft + sa * 64 + hbase);
        uint2 rb = *(const uint2*)(ft + sb * 64 + hbase);
        floatx4 ha = unpack4(ra), hb = unpack4(rb);
        float pa = ha.x * hd.x + ha.y * hd.y + ha.z * hd.z + ha.w * hd.w;
        float pb = hb.x * hd.x + hb.y * hd.y + hb.z * hd.z + hb.w * hd.w;
        pa += __shfl_xor(pa, 1); pb += __shfl_xor(pb, 1);
        pa += __shfl_xor(pa, 2); pb += __shfl_xor(pb, 2);
        pa += __shfl_xor(pa, 4); pb += __shfl_xor(pb, 4);
        pa += __shfl_xor(pa, 8); pb += __shfl_xor(pb, 8);
        float wa = __expf(pa * 0.125f);
        float wb = __expf(pb * 0.125f);
        l += wa + wb;
        acc.x += wa * ha.x + wb * hb.x;
        acc.y += wa * ha.y + wb * hb.y;
        acc.z += wa * ha.z + wb * hb.z;
        acc.w += wa * ha.w + wb * hb.w;
    }
    for (; e0 < end; e0 += 4) {
        int e = e0 + g;
        bool valid = (e < end);
        int sn = valid ? csr[e] : 0;
        floatx4 hs = unpack4(*(const uint2*)(ft + sn * 64 + hbase));
        float p = hs.x * hd.x + hs.y * hd.y + hs.z * hd.z + hs.w * hd.w;
        p += __shfl_xor(p, 1); p += __shfl_xor(p, 2);
        p += __shfl_xor(p, 4); p += __shfl_xor(p, 8);
        float wgt = valid ? __expf(p * 0.125f) : 0.f;
        l += wgt;
        acc.x += wgt * hs.x; acc.y += wgt * hs.y;
        acc.z += wgt * hs.z; acc.w += wgt * hs.w;
    }
    l += __shfl_xor(l, 16); l += __shfl_xor(l, 32);
    acc.x += __shfl_xor(acc.x, 16); acc.x += __shfl_xor(acc.x, 32);
    acc.y += __shfl_xor(acc.y, 16); acc.y += __shfl_xor(acc.y, 32);
    acc.z += __shfl_xor(acc.z, 16); acc.z += __shfl_xor(acc.z, 32);
    acc.w += __shfl_xor(acc.w, 16); acc.w += __shfl_xor(acc.w, 32);
    float inv = (l > 0.f) ? 1.f / l : 0.f;
    if (g == 0) {
        floatx4 o = {fmaxf(acc.x * inv, 0.f), fmaxf(acc.y * inv, 0.f),
                     fmaxf(acc.z * inv, 0.f), fmaxf(acc.w * inv, 0.f)};
        *(floatx4*)(out + dstv * 64 + hbase) = o;
    }
}

// ---------- fused mean-pool + classifier: 1 block / graph (gid sorted) ----------
__global__ __launch_bounds__(256) void poolclass_kernel(const float* __restrict__ x,
                                                        const int* __restrict__ gid,
                                                        const float* __restrict__ Wc,
                                                        const float* __restrict__ bc,
                                                        void* out, const int* flag) {
    __shared__ int s_lo, s_hi;
    __shared__ float part[4][64];
    int g = blockIdx.x;
    int tid = threadIdx.x;
    if (tid == 0) {
        int lo = 0, hi = N_NODES;
        while (lo < hi) { int m = (lo + hi) >> 1; if (gid[m] < g) lo = m + 1; else hi = m; }
        s_lo = lo;
        int lo2 = lo, hi2 = N_NODES;
        while (lo2 < hi2) { int m = (lo2 + hi2) >> 1; if (gid[m] < g + 1) lo2 = m + 1; else hi2 = m; }
        s_hi = lo2;
    }
    __syncthreads();
    int lo = s_lo, hi = s_hi;
    int d = tid & 63, w = tid >> 6;
    float sum = 0.f;
    for (int n = lo + w; n < hi; n += 4) sum += x[n * 64 + d];
    part[w][d] = sum;
    __syncthreads();
    if (w == 0) {
        float tot = part[0][d] + part[1][d] + part[2][d] + part[3][d];
        int cntg = hi - lo;
        float mean = (cntg > 0) ? tot / (float)cntg : 0.f;
        for (int cls = 0; cls < N_CLASSES; ++cls) {
            float p = mean * Wc[d * N_CLASSES + cls];
#pragma unroll
            for (int o = 1; o < 64; o <<= 1) p += __shfl_xor(p, o);
            if (d == 0) {
                float r = p + bc[cls];
                if (*flag) ((__hip_bfloat16*)out)[g * N_CLASSES + cls] = __float2bfloat16(r);
                else       ((float*)out)[g * N_CLASSES + cls] = r;
            }
        }
    }
}

static inline size_t align256(size_t x) { return (x + 255) & ~size_t(255); }

extern "C" void kernel_launch(void* const* d_in, const int* in_sizes, int n_in,
                              void* d_out, int out_size, void* d_ws, size_t ws_size,
                              hipStream_t stream) {
    const void* h_raw  = d_in[0];
    const int*  src    = (const int*)d_in[1];
    const int*  dst    = (const int*)d_in[2];
    const int*  gid    = (const int*)d_in[3];
    const void* W1_raw = d_in[4];
    const void* W2_raw = d_in[5];
    const void* Wc_raw = d_in[6];
    const void* bc_raw = d_in[7];

    // ---- workspace layout ----
    char* w = (char*)d_ws;
    int*  flag     = (int*)w;                      w += 256;
    int*  cnt      = (int*)w;                      w += align256(N_NODES * 4);
    int*  off      = (int*)w;                      w += align256((N_NODES + 1) * 4);
    int*  off_work = (int*)w;                      w += align256(N_NODES * 4);
    int*  csr_src  = (int*)w;                      w += align256(N_EDGES * 4);
    unsigned short* W1t = (unsigned short*)w;      w += align256(256 * 128 * 2);
    unsigned short* W2t = (unsigned short*)w;      w += align256(64 * 256 * 2);
    float* Wcf     = (float*)w;                    w += align256(HID * N_CLASSES * 4);
    float* bcf     = (float*)w;                    w += 256;
    unsigned short* h_b  = (unsigned short*)w;     w += align256((size_t)N_NODES * IN_DIM * 2);
    unsigned short* ft1  = (unsigned short*)w;     w += align256((size_t)N_NODES * 256 * 2);
    unsigned short* ft2  = (unsigned short*)w;     w += align256((size_t)N_NODES * HID * 2);
    float* x2      = (float*)w;                    w += align256((size_t)N_NODES * HID * 4);

    // 1) init: detect (block 0) + zero cnt
    hipLaunchKernelGGL(init_kernel, dim3(1 + (N_NODES + 255) / 256), dim3(256), 0, stream,
                       (const unsigned int*)h_raw, 4096, flag,
                       (unsigned int*)cnt, N_NODES);

    // 2) fused prep: convW (195) + convH-if-f32 (640) + count (1250)
    hipLaunchKernelGGL(prep_kernel, dim3(195 + 640 + 1250), dim3(256), 0, stream,
                       W1_raw, W2_raw, Wc_raw, bc_raw, W1t, W2t, Wcf, bcf,
                       h_raw, h_b, dst, cnt, flag);

    // 3) CSR scan
    hipLaunchKernelGGL(scan_kernel, dim3(1), dim3(1024), 0, stream, cnt, off, off_work, N_NODES);

    // 4) fused fill (1250) + gemm1 (313)
    hipLaunchKernelGGL(fillgemm1_kernel, dim3(1250 + 313), dim3(256), 0, stream,
                       src, dst, off_work, csr_src,
                       h_raw, h_b, W1t, ft1, flag);

    // 5) attention layer 1 + fused layer-2 GEMM row -> ft2 (bf16)
    hipLaunchKernelGGL(attn_h4_kernel, dim3(N_NODES / 4), dim3(256), 0, stream,
                       ft1, off, csr_src, W2t, ft2);

    // 6) attention layer 2 -> x2 (f32)
    hipLaunchKernelGGL(attn_h1_kernel, dim3(N_NODES / 4), dim3(256), 0, stream,
                       ft2, off, csr_src, x2);

    // 7) fused mean-pool + classifier -> d_out
    hipLaunchKernelGGL(poolclass_kernel, dim3(NUM_GRAPHS), dim3(256), 0, stream,
                       x2, gid, Wcf, bcf, d_out, flag);
}

// Round 10
// 216.053 us; speedup vs baseline: 1.2611x; 1.2611x over previous
//
#include <hip/hip_runtime.h>
#include <hip/hip_bf16.h>

typedef __attribute__((ext_vector_type(8))) __bf16 bf16x8;
typedef __attribute__((ext_vector_type(4))) float floatx4;

#define N_NODES   20000
#define N_EDGES   320000
#define IN_DIM    128
#define HID       64
#define HEADS     4
#define NUM_GRAPHS 128
#define N_CLASSES 10

__device__ inline float cvt_load(const void* p, int i, int isb) {
    return isb ? __bfloat162float(((const __hip_bfloat16*)p)[i]) : ((const float*)p)[i];
}

__device__ inline unsigned short bf16bits(float v) {
    return __builtin_bit_cast(unsigned short, __float2bfloat16(v));
}

__device__ inline unsigned pack2(float a, float b) {
    return (unsigned)bf16bits(a) | ((unsigned)bf16bits(b) << 16);
}

__device__ inline floatx4 unpack4(uint2 u) {
    floatx4 f;
    f.x = __uint_as_float(u.x << 16);
    f.y = __uint_as_float(u.x & 0xffff0000u);
    f.z = __uint_as_float(u.y << 16);
    f.w = __uint_as_float(u.y & 0xffff0000u);
    return f;
}

// ---------- init: block 0 = dtype detect; remaining blocks zero cnt ----------
__global__ void init_kernel(const unsigned int* hw, int nwords, int* flag,
                            unsigned int* cnt, int n1) {
    int b = blockIdx.x;
    if (b == 0) {
        __shared__ int s_bad;
        if (threadIdx.x == 0) s_bad = 0;
        __syncthreads();
        int bad = 0;
        for (int i = threadIdx.x; i < nwords; i += 256) {
            float v = __uint_as_float(hw[i]);
            if (!(fabsf(v) <= 1e20f)) bad = 1;
        }
        if (bad) atomicOr(&s_bad, 1);
        __syncthreads();
        if (threadIdx.x == 0) *flag = s_bad;
    } else {
        int i = (b - 1) * 256 + threadIdx.x;
        if (i < n1) cnt[i] = 0u;
    }
}

// ---------- fused prep: convW [0,195) | convH-if-f32 [195,835) | count [835,2085) ----------
__global__ void prep_kernel(const void* W1, const void* W2, const void* Wc, const void* bc,
                            unsigned short* W1t, unsigned short* W2t, float* Wcf, float* bcf,
                            const void* h, unsigned short* hb,
                            const int* __restrict__ dst, int* __restrict__ cnt,
                            const int* flag) {
    int b = blockIdx.x;
    const int n1 = IN_DIM * HID * HEADS;        // 32768
    const int n2 = HID * HEADS * HID;           // 16384
    const int n3 = HID * N_CLASSES;             // 640
    const int n4 = N_CLASSES;                   // 10
    if (b < 195) {
        int i = b * 256 + threadIdx.x;
        int isb = *flag;
        if (i < n1) {
            int k = i >> 8, n = i & 255;            // W1[k][n]
            W1t[n * 128 + k] = bf16bits(cvt_load(W1, i, isb));
        } else if (i < n1 + n2) {
            int j = i - n1;
            int k = j >> 6, n = j & 63;             // W2[k][n]
            W2t[n * 256 + k] = bf16bits(cvt_load(W2, j, isb));
        } else if (i < n1 + n2 + n3) {
            int j = i - n1 - n2;
            Wcf[j] = cvt_load(Wc, j, isb);
        } else if (i < n1 + n2 + n3 + n4) {
            int j = i - n1 - n2 - n3;
            bcf[j] = cvt_load(bc, j, isb);
        }
    } else if (b < 195 + 640) {
        int isb = *flag;
        if (!isb) {
            int base = (b - 195) * 4096;
            for (int t = 0; t < 16; ++t) {
                int i = base + t * 256 + threadIdx.x;
                if (i < N_NODES * IN_DIM) hb[i] = bf16bits(cvt_load(h, i, 0));
            }
        }
    } else {
        int e = (b - 835) * 256 + threadIdx.x;
        if (e < N_EDGES) atomicAdd(&cnt[dst[e]], 1);
    }
}

// ---------- scan (proven): 1024 threads, 20 elem/thread serial + one block scan ----------
__global__ void scan_kernel(const int* __restrict__ cnt, int* __restrict__ off,
                            int* __restrict__ off_work, int n) {
    const int CH = 20;
    __shared__ int wsum[16];
    int tid  = threadIdx.x;
    int lane = tid & 63;
    int w    = tid >> 6;
    int base = tid * CH;
    int local[CH];
    int s = 0;
#pragma unroll
    for (int i = 0; i < CH; ++i) {
        int idx = base + i;
        int v = (idx < n) ? cnt[idx] : 0;
        local[i] = s;
        s += v;
    }
    int x = s;
#pragma unroll
    for (int sh = 1; sh < 64; sh <<= 1) {
        int t = __shfl_up(x, sh);
        if (lane >= sh) x += t;
    }
    if (lane == 63) wsum[w] = x;
    __syncthreads();
    if (w == 0 && lane < 16) {
        int y = wsum[lane];
#pragma unroll
        for (int sh = 1; sh < 16; sh <<= 1) {
            int t = __shfl_up(y, sh);
            if (lane >= sh) y += t;
        }
        wsum[lane] = y;
    }
    __syncthreads();
    int thread_off = ((w > 0) ? wsum[w - 1] : 0) + (x - s);
#pragma unroll
    for (int i = 0; i < CH; ++i) {
        int idx = base + i;
        if (idx < n) {
            int e = thread_off + local[i];
            off[idx] = e;
            off_work[idx] = e;
        }
    }
    if (tid == 1023) off[n] = thread_off + s;
}

// ---------- fused fill [0,1250) + gemm1 [1250,1563): independent phases (R9-proven) ----------
__global__ __launch_bounds__(256) void fillgemm1_kernel(
        const int* __restrict__ src, const int* __restrict__ dst,
        int* __restrict__ off_work, int* __restrict__ csr_src,
        const void* __restrict__ h_any, const unsigned short* __restrict__ h_b,
        const unsigned short* __restrict__ Bt, unsigned short* __restrict__ C,
        const int* flag) {
    int b = blockIdx.x;
    if (b < 1250) {
        int e = b * 256 + threadIdx.x;
        if (e < N_EDGES) {
            int d = dst[e];
            int pos = atomicAdd(&off_work[d], 1);
            csr_src[pos] = src[e];
        }
        return;
    }
    // ---- gemm1: ft1[M,256] = A[M,128] @ W1 ----
    const int M = N_NODES;
    const unsigned short* A = (*flag) ? (const unsigned short*)h_any : h_b;
    int wave = threadIdx.x >> 6;
    int lane = threadIdx.x & 63;
    int q = lane >> 4, r = lane & 15;
    int m0 = (b - 1250) * 64;
    int n0 = wave * 64;
    floatx4 acc[4][4] = {};
    bf16x8 bfrag[4][4];
#pragma unroll
    for (int ni = 0; ni < 4; ++ni)
#pragma unroll
        for (int kk = 0; kk < 4; ++kk)
            bfrag[ni][kk] = *(const bf16x8*)(Bt + (n0 + ni * 16 + r) * 128 + kk * 32 + q * 8);
#pragma unroll
    for (int kk = 0; kk < 4; ++kk) {
        bf16x8 afrag[4];
#pragma unroll
        for (int mi = 0; mi < 4; ++mi) {
            int row = m0 + mi * 16 + r;
            bf16x8 a = {};
            if (row < M) a = *(const bf16x8*)(A + row * 128 + kk * 32 + q * 8);
            afrag[mi] = a;
        }
#pragma unroll
        for (int mi = 0; mi < 4; ++mi)
#pragma unroll
            for (int ni = 0; ni < 4; ++ni)
                acc[mi][ni] = __builtin_amdgcn_mfma_f32_16x16x32_bf16(afrag[mi], bfrag[ni][kk], acc[mi][ni], 0, 0, 0);
    }
#pragma unroll
    for (int mi = 0; mi < 4; ++mi)
#pragma unroll
        for (int rr = 0; rr < 4; ++rr) {
            int row = m0 + mi * 16 + q * 4 + rr;
            if (row < M) {
#pragma unroll
                for (int ni = 0; ni < 4; ++ni)
                    C[row * 256 + n0 + ni * 16 + r] = bf16bits(acc[mi][ni][rr]);
            }
        }
}

// ---------- attention H=4 (R8-proven): wave = dst, all 4 heads, unroll-4, writes x1 bf16 ----------
__global__ __launch_bounds__(256) void attn_h4_kernel(const unsigned short* __restrict__ ft,
                                                      const int* __restrict__ off,
                                                      const int* __restrict__ csr,
                                                      unsigned short* __restrict__ out) {
    int dstv = blockIdx.x * 4 + (threadIdx.x >> 6);
    int lane = threadIdx.x & 63;
    floatx4 hd = unpack4(*(const uint2*)(ft + dstv * 256 + lane * 4));
    int beg = off[dstv], end = off[dstv + 1];
    float l = 0.f;
    floatx4 acc = {0.f, 0.f, 0.f, 0.f};
    int e = beg;
    for (; e + 4 <= end; e += 4) {
        int sn0 = csr[e], sn1 = csr[e + 1], sn2 = csr[e + 2], sn3 = csr[e + 3];
        uint2 r0 = *(const uint2*)(ft + sn0 * 256 + lane * 4);
        uint2 r1 = *(const uint2*)(ft + sn1 * 256 + lane * 4);
        uint2 r2 = *(const uint2*)(ft + sn2 * 256 + lane * 4);
        uint2 r3 = *(const uint2*)(ft + sn3 * 256 + lane * 4);
        floatx4 h0 = unpack4(r0), h1 = unpack4(r1), h2 = unpack4(r2), h3 = unpack4(r3);
        float p0 = h0.x * hd.x + h0.y * hd.y + h0.z * hd.z + h0.w * hd.w;
        float p1 = h1.x * hd.x + h1.y * hd.y + h1.z * hd.z + h1.w * hd.w;
        float p2 = h2.x * hd.x + h2.y * hd.y + h2.z * hd.z + h2.w * hd.w;
        float p3 = h3.x * hd.x + h3.y * hd.y + h3.z * hd.z + h3.w * hd.w;
        p0 += __shfl_xor(p0, 1); p1 += __shfl_xor(p1, 1); p2 += __shfl_xor(p2, 1); p3 += __shfl_xor(p3, 1);
        p0 += __shfl_xor(p0, 2); p1 += __shfl_xor(p1, 2); p2 += __shfl_xor(p2, 2); p3 += __shfl_xor(p3, 2);
        p0 += __shfl_xor(p0, 4); p1 += __shfl_xor(p1, 4); p2 += __shfl_xor(p2, 4); p3 += __shfl_xor(p3, 4);
        p0 += __shfl_xor(p0, 8); p1 += __shfl_xor(p1, 8); p2 += __shfl_xor(p2, 8); p3 += __shfl_xor(p3, 8);
        float w0 = __expf(p0 * 0.125f);
        float w1 = __expf(p1 * 0.125f);
        float w2 = __expf(p2 * 0.125f);
        float w3 = __expf(p3 * 0.125f);
        l += (w0 + w1) + (w2 + w3);
        acc.x += w0 * h0.x + w1 * h1.x + w2 * h2.x + w3 * h3.x;
        acc.y += w0 * h0.y + w1 * h1.y + w2 * h2.y + w3 * h3.y;
        acc.z += w0 * h0.z + w1 * h1.z + w2 * h2.z + w3 * h3.z;
        acc.w += w0 * h0.w + w1 * h1.w + w2 * h2.w + w3 * h3.w;
    }
    for (; e < end; ++e) {
        int sn = csr[e];
        floatx4 hs = unpack4(*(const uint2*)(ft + sn * 256 + lane * 4));
        float p = hs.x * hd.x + hs.y * hd.y + hs.z * hd.z + hs.w * hd.w;
        p += __shfl_xor(p, 1); p += __shfl_xor(p, 2);
        p += __shfl_xor(p, 4); p += __shfl_xor(p, 8);
        float wgt = __expf(p * 0.125f);
        l += wgt;
        acc.x += wgt * hs.x; acc.y += wgt * hs.y;
        acc.z += wgt * hs.z; acc.w += wgt * hs.w;
    }
    float inv = (l > 0.f) ? 1.f / l : 0.f;
    uint2 o;
    o.x = pack2(fmaxf(acc.x * inv, 0.f), fmaxf(acc.y * inv, 0.f));
    o.y = pack2(fmaxf(acc.z * inv, 0.f), fmaxf(acc.w * inv, 0.f));
    *(uint2*)(out + dstv * 256 + lane * 4) = o;
}

// ---------- GEMM2 (MFMA, R8-proven): ft2[M,64] = x1[M,256] @ W2 ----------
__global__ __launch_bounds__(256) void gemm2_kernel(const unsigned short* __restrict__ A,
                                                    const unsigned short* __restrict__ Bt,
                                                    unsigned short* __restrict__ C, int M) {
    int wave = threadIdx.x >> 6;
    int lane = threadIdx.x & 63;
    int q = lane >> 4, r = lane & 15;
    int m0 = blockIdx.x * 256 + wave * 64;
    floatx4 acc[4][4] = {};
#pragma unroll
    for (int kk = 0; kk < 8; ++kk) {
        bf16x8 bfrag[4], afrag[4];
#pragma unroll
        for (int ni = 0; ni < 4; ++ni)
            bfrag[ni] = *(const bf16x8*)(Bt + (ni * 16 + r) * 256 + kk * 32 + q * 8);
#pragma unroll
        for (int mi = 0; mi < 4; ++mi) {
            int row = m0 + mi * 16 + r;
            bf16x8 a = {};
            if (row < M) a = *(const bf16x8*)(A + row * 256 + kk * 32 + q * 8);
            afrag[mi] = a;
        }
#pragma unroll
        for (int mi = 0; mi < 4; ++mi)
#pragma unroll
            for (int ni = 0; ni < 4; ++ni)
                acc[mi][ni] = __builtin_amdgcn_mfma_f32_16x16x32_bf16(afrag[mi], bfrag[ni], acc[mi][ni], 0, 0, 0);
    }
#pragma unroll
    for (int mi = 0; mi < 4; ++mi)
#pragma unroll
        for (int rr = 0; rr < 4; ++rr) {
            int row = m0 + mi * 16 + q * 4 + rr;
            if (row < M) {
#pragma unroll
                for (int ni = 0; ni < 4; ++ni)
                    C[row * 64 + ni * 16 + r] = bf16bits(acc[mi][ni][rr]);
            }
        }
}

// ---------- attention H=1 (proven): wave = dst, 4 edge-groups x 16 lanes, unroll-2 ----------
__global__ __launch_bounds__(256) void attn_h1_kernel(const unsigned short* __restrict__ ft,
                                                      const int* __restrict__ off,
                                                      const int* __restrict__ csr,
                                                      float* __restrict__ out) {
    int dstv = blockIdx.x * 4 + (threadIdx.x >> 6);
    int lane = threadIdx.x & 63;
    int g = lane >> 4, s = lane & 15;
    int hbase = s * 4;
    floatx4 hd = unpack4(*(const uint2*)(ft + dstv * 64 + hbase));
    int beg = off[dstv], end = off[dstv + 1];
    float l = 0.f;
    floatx4 acc = {0.f, 0.f, 0.f, 0.f};
    int e0 = beg;
    for (; e0 + 8 <= end; e0 += 8) {
        int ea = e0 + g, eb = e0 + 4 + g;
        int sa = csr[ea], sb = csr[eb];
        uint2 ra = *(const uint2*)(ft + sa * 64 + hbase);
        uint2 rb = *(const uint2*)(ft + sb * 64 + hbase);
        floatx4 ha = unpack4(ra), hb = unpack4(rb);
        float pa = ha.x * hd.x + ha.y * hd.y + ha.z * hd.z + ha.w * hd.w;
        float pb = hb.x * hd.x + hb.y * hd.y + hb.z * hd.z + hb.w * hd.w;
        pa += __shfl_xor(pa, 1); pb += __shfl_xor(pb, 1);
        pa += __shfl_xor(pa, 2); pb += __shfl_xor(pb, 2);
        pa += __shfl_xor(pa, 4); pb += __shfl_xor(pb, 4);
        pa += __shfl_xor(pa, 8); pb += __shfl_xor(pb, 8);
        float wa = __expf(pa * 0.125f);
        float wb = __expf(pb * 0.125f);
        l += wa + wb;
        acc.x += wa * ha.x + wb * hb.x;
        acc.y += wa * ha.y + wb * hb.y;
        acc.z += wa * ha.z + wb * hb.z;
        acc.w += wa * ha.w + wb * hb.w;
    }
    for (; e0 < end; e0 += 4) {
        int e = e0 + g;
        bool valid = (e < end);
        int sn = valid ? csr[e] : 0;
        floatx4 hs = unpack4(*(const uint2*)(ft + sn * 64 + hbase));
        float p = hs.x * hd.x + hs.y * hd.y + hs.z * hd.z + hs.w * hd.w;
        p += __shfl_xor(p, 1); p += __shfl_xor(p, 2);
        p += __shfl_xor(p, 4); p += __shfl_xor(p, 8);
        float wgt = valid ? __expf(p * 0.125f) : 0.f;
        l += wgt;
        acc.x += wgt * hs.x; acc.y += wgt * hs.y;
        acc.z += wgt * hs.z; acc.w += wgt * hs.w;
    }
    l += __shfl_xor(l, 16); l += __shfl_xor(l, 32);
    acc.x += __shfl_xor(acc.x, 16); acc.x += __shfl_xor(acc.x, 32);
    acc.y += __shfl_xor(acc.y, 16); acc.y += __shfl_xor(acc.y, 32);
    acc.z += __shfl_xor(acc.z, 16); acc.z += __shfl_xor(acc.z, 32);
    acc.w += __shfl_xor(acc.w, 16); acc.w += __shfl_xor(acc.w, 32);
    float inv = (l > 0.f) ? 1.f / l : 0.f;
    if (g == 0) {
        floatx4 o = {fmaxf(acc.x * inv, 0.f), fmaxf(acc.y * inv, 0.f),
                     fmaxf(acc.z * inv, 0.f), fmaxf(acc.w * inv, 0.f)};
        *(floatx4*)(out + dstv * 64 + hbase) = o;
    }
}

// ---------- fused mean-pool + classifier (R9-proven): 1 block / graph ----------
__global__ __launch_bounds__(256) void poolclass_kernel(const float* __restrict__ x,
                                                        const int* __restrict__ gid,
                                                        const float* __restrict__ Wc,
                                                        const float* __restrict__ bc,
                                                        void* out, const int* flag) {
    __shared__ int s_lo, s_hi;
    __shared__ float part[4][64];
    int g = blockIdx.x;
    int tid = threadIdx.x;
    if (tid == 0) {
        int lo = 0, hi = N_NODES;
        while (lo < hi) { int m = (lo + hi) >> 1; if (gid[m] < g) lo = m + 1; else hi = m; }
        s_lo = lo;
        int lo2 = lo, hi2 = N_NODES;
        while (lo2 < hi2) { int m = (lo2 + hi2) >> 1; if (gid[m] < g + 1) lo2 = m + 1; else hi2 = m; }
        s_hi = lo2;
    }
    __syncthreads();
    int lo = s_lo, hi = s_hi;
    int d = tid & 63, w = tid >> 6;
    float sum = 0.f;
    for (int n = lo + w; n < hi; n += 4) sum += x[n * 64 + d];
    part[w][d] = sum;
    __syncthreads();
    if (w == 0) {
        float tot = part[0][d] + part[1][d] + part[2][d] + part[3][d];
        int cntg = hi - lo;
        float mean = (cntg > 0) ? tot / (float)cntg : 0.f;
        for (int cls = 0; cls < N_CLASSES; ++cls) {
            float p = mean * Wc[d * N_CLASSES + cls];
#pragma unroll
            for (int o = 1; o < 64; o <<= 1) p += __shfl_xor(p, o);
            if (d == 0) {
                float r = p + bc[cls];
                if (*flag) ((__hip_bfloat16*)out)[g * N_CLASSES + cls] = __float2bfloat16(r);
                else       ((float*)out)[g * N_CLASSES + cls] = r;
            }
        }
    }
}

static inline size_t align256(size_t x) { return (x + 255) & ~size_t(255); }

extern "C" void kernel_launch(void* const* d_in, const int* in_sizes, int n_in,
                              void* d_out, int out_size, void* d_ws, size_t ws_size,
                              hipStream_t stream) {
    const void* h_raw  = d_in[0];
    const int*  src    = (const int*)d_in[1];
    const int*  dst    = (const int*)d_in[2];
    const int*  gid    = (const int*)d_in[3];
    const void* W1_raw = d_in[4];
    const void* W2_raw = d_in[5];
    const void* Wc_raw = d_in[6];
    const void* bc_raw = d_in[7];

    // ---- workspace layout ----
    char* w = (char*)d_ws;
    int*  flag     = (int*)w;                      w += 256;
    int*  cnt      = (int*)w;                      w += align256(N_NODES * 4);
    int*  off      = (int*)w;                      w += align256((N_NODES + 1) * 4);
    int*  off_work = (int*)w;                      w += align256(N_NODES * 4);
    int*  csr_src  = (int*)w;                      w += align256(N_EDGES * 4);
    unsigned short* W1t = (unsigned short*)w;      w += align256(256 * 128 * 2);
    unsigned short* W2t = (unsigned short*)w;      w += align256(64 * 256 * 2);
    float* Wcf     = (float*)w;                    w += align256(HID * N_CLASSES * 4);
    float* bcf     = (float*)w;                    w += 256;
    unsigned short* h_b  = (unsigned short*)w;     w += align256((size_t)N_NODES * IN_DIM * 2);
    unsigned short* ft1  = (unsigned short*)w;     w += align256((size_t)N_NODES * 256 * 2);
    unsigned short* x1   = (unsigned short*)w;     w += align256((size_t)N_NODES * 256 * 2);
    unsigned short* ft2  = (unsigned short*)w;     w += align256((size_t)N_NODES * HID * 2);
    float* x2      = (float*)w;                    w += align256((size_t)N_NODES * HID * 4);

    // 1) init: detect (block 0) + zero cnt
    hipLaunchKernelGGL(init_kernel, dim3(1 + (N_NODES + 255) / 256), dim3(256), 0, stream,
                       (const unsigned int*)h_raw, 4096, flag,
                       (unsigned int*)cnt, N_NODES);

    // 2) fused prep: convW (195) + convH-if-f32 (640) + count (1250)
    hipLaunchKernelGGL(prep_kernel, dim3(195 + 640 + 1250), dim3(256), 0, stream,
                       W1_raw, W2_raw, Wc_raw, bc_raw, W1t, W2t, Wcf, bcf,
                       h_raw, h_b, dst, cnt, flag);

    // 3) CSR scan
    hipLaunchKernelGGL(scan_kernel, dim3(1), dim3(1024), 0, stream, cnt, off, off_work, N_NODES);

    // 4) fused fill (1250) + gemm1 (313)
    hipLaunchKernelGGL(fillgemm1_kernel, dim3(1250 + 313), dim3(256), 0, stream,
                       src, dst, off_work, csr_src,
                       h_raw, h_b, W1t, ft1, flag);

    // 5) attention layer 1 -> x1 (bf16)   [R8-proven kernel]
    hipLaunchKernelGGL(attn_h4_kernel, dim3(N_NODES / 4), dim3(256), 0, stream,
                       ft1, off, csr_src, x1);

    // 6) layer 2 GEMM (MFMA)  [R8-proven kernel]
    hipLaunchKernelGGL(gemm2_kernel, dim3((N_NODES + 255) / 256), dim3(256), 0, stream,
                       x1, W2t, ft2, N_NODES);

    // 7) attention layer 2 -> x2 (f32)
    hipLaunchKernelGGL(attn_h1_kernel, dim3(N_NODES / 4), dim3(256), 0, stream,
                       ft2, off, csr_src, x2);

    // 8) fused mean-pool + classifier -> d_out
    hipLaunchKernelGGL(poolclass_kernel, dim3(NUM_GRAPHS), dim3(256), 0, stream,
                       x2, gid, Wcf, bcf, d_out, flag);
}

// Round 11
// 190.157 us; speedup vs baseline: 1.4329x; 1.1362x over previous
//
#include <hip/hip_runtime.h>
#include <hip/hip_bf16.h>

typedef __attribute__((ext_vector_type(8))) __bf16 bf16x8;
typedef __attribute__((ext_vector_type(4))) float floatx4;

#define N_NODES   20000
#define N_EDGES   320000
#define IN_DIM    128
#define HID       64
#define HEADS     4
#define NUM_GRAPHS 128
#define N_CLASSES 10
#define BCAP      128     // bucket slots/node; deg~Poisson(16), P(>128)~1e-60

__device__ inline float cvt_load(const void* p, int i, int isb) {
    return isb ? __bfloat162float(((const __hip_bfloat16*)p)[i]) : ((const float*)p)[i];
}

__device__ inline unsigned short bf16bits(float v) {
    return __builtin_bit_cast(unsigned short, __float2bfloat16(v));
}

__device__ inline unsigned pack2(float a, float b) {
    return (unsigned)bf16bits(a) | ((unsigned)bf16bits(b) << 16);
}

__device__ inline floatx4 unpack4(uint2 u) {
    floatx4 f;
    f.x = __uint_as_float(u.x << 16);
    f.y = __uint_as_float(u.x & 0xffff0000u);
    f.z = __uint_as_float(u.y << 16);
    f.w = __uint_as_float(u.y & 0xffff0000u);
    return f;
}

// ---------- init: block 0 = dtype detect; remaining blocks zero cnt ----------
__global__ void init_kernel(const unsigned int* hw, int nwords, int* flag,
                            unsigned int* cnt, int n1) {
    int b = blockIdx.x;
    if (b == 0) {
        __shared__ int s_bad;
        if (threadIdx.x == 0) s_bad = 0;
        __syncthreads();
        int bad = 0;
        for (int i = threadIdx.x; i < nwords; i += 256) {
            float v = __uint_as_float(hw[i]);
            if (!(fabsf(v) <= 1e20f)) bad = 1;
        }
        if (bad) atomicOr(&s_bad, 1);
        __syncthreads();
        if (threadIdx.x == 0) *flag = s_bad;
    } else {
        int i = (b - 1) * 256 + threadIdx.x;
        if (i < n1) cnt[i] = 0u;
    }
}

// ---------- fused prep: convW [0,195) | convH-if-f32 [195,835) | bucket-fill [835,2085) ----------
__global__ void prep_kernel(const void* W1, const void* W2, const void* Wc, const void* bc,
                            unsigned short* W1t, unsigned short* W2t, float* Wcf, float* bcf,
                            const void* h, unsigned short* hb,
                            const int* __restrict__ src, const int* __restrict__ dst,
                            int* __restrict__ cnt, int* __restrict__ bucket,
                            const int* flag) {
    int b = blockIdx.x;
    const int n1 = IN_DIM * HID * HEADS;        // 32768
    const int n2 = HID * HEADS * HID;           // 16384
    const int n3 = HID * N_CLASSES;             // 640
    const int n4 = N_CLASSES;                   // 10
    if (b < 195) {
        int i = b * 256 + threadIdx.x;
        int isb = *flag;
        if (i < n1) {
            int k = i >> 8, n = i & 255;            // W1[k][n]
            W1t[n * 128 + k] = bf16bits(cvt_load(W1, i, isb));
        } else if (i < n1 + n2) {
            int j = i - n1;
            int k = j >> 6, n = j & 63;             // W2[k][n]
            W2t[n * 256 + k] = bf16bits(cvt_load(W2, j, isb));
        } else if (i < n1 + n2 + n3) {
            int j = i - n1 - n2;
            Wcf[j] = cvt_load(Wc, j, isb);
        } else if (i < n1 + n2 + n3 + n4) {
            int j = i - n1 - n2 - n3;
            bcf[j] = cvt_load(bc, j, isb);
        }
    } else if (b < 195 + 640) {
        int isb = *flag;
        if (!isb) {
            int base = (b - 195) * 4096;
            for (int t = 0; t < 16; ++t) {
                int i = base + t * 256 + threadIdx.x;
                if (i < N_NODES * IN_DIM) hb[i] = bf16bits(cvt_load(h, i, 0));
            }
        }
    } else {
        int e = (b - 835) * 256 + threadIdx.x;
        if (e < N_EDGES) {
            int d = dst[e];
            int pos = atomicAdd(&cnt[d], 1);
            if (pos < BCAP) bucket[d * BCAP + pos] = src[e];
        }
    }
}

// ---------- GEMM1 (MFMA, proven): ft1[M,256] = A[M,128] @ W1 ----------
__global__ __launch_bounds__(256) void gemm1_kernel(const void* __restrict__ h_any,
                                                    const unsigned short* __restrict__ h_b,
                                                    const unsigned short* __restrict__ Bt,
                                                    unsigned short* __restrict__ C, int M,
                                                    const int* flag) {
    const unsigned short* A = (*flag) ? (const unsigned short*)h_any : h_b;
    int wave = threadIdx.x >> 6;
    int lane = threadIdx.x & 63;
    int q = lane >> 4, r = lane & 15;
    int m0 = blockIdx.x * 64;
    int n0 = wave * 64;
    floatx4 acc[4][4] = {};
    bf16x8 bfrag[4][4];
#pragma unroll
    for (int ni = 0; ni < 4; ++ni)
#pragma unroll
        for (int kk = 0; kk < 4; ++kk)
            bfrag[ni][kk] = *(const bf16x8*)(Bt + (n0 + ni * 16 + r) * 128 + kk * 32 + q * 8);
#pragma unroll
    for (int kk = 0; kk < 4; ++kk) {
        bf16x8 afrag[4];
#pragma unroll
        for (int mi = 0; mi < 4; ++mi) {
            int row = m0 + mi * 16 + r;
            bf16x8 a = {};
            if (row < M) a = *(const bf16x8*)(A + row * 128 + kk * 32 + q * 8);
            afrag[mi] = a;
        }
#pragma unroll
        for (int mi = 0; mi < 4; ++mi)
#pragma unroll
            for (int ni = 0; ni < 4; ++ni)
                acc[mi][ni] = __builtin_amdgcn_mfma_f32_16x16x32_bf16(afrag[mi], bfrag[ni][kk], acc[mi][ni], 0, 0, 0);
    }
#pragma unroll
    for (int mi = 0; mi < 4; ++mi)
#pragma unroll
        for (int rr = 0; rr < 4; ++rr) {
            int row = m0 + mi * 16 + q * 4 + rr;
            if (row < M) {
#pragma unroll
                for (int ni = 0; ni < 4; ++ni)
                    C[row * 256 + n0 + ni * 16 + r] = bf16bits(acc[mi][ni][rr]);
            }
        }
}

// ---------- attention H=4: TWO WAVES per dst (even/odd 4-edge chunks), LDS merge ----------
__global__ __launch_bounds__(256) void attn_h4_kernel(const unsigned short* __restrict__ ft,
                                                      const int* __restrict__ cnt,
                                                      const int* __restrict__ bucket,
                                                      unsigned short* __restrict__ out) {
    __shared__ float   s_l[2][64];
    __shared__ floatx4 s_acc[2][64];
    int w    = threadIdx.x >> 6;
    int dl   = w >> 1;            // dst slot in block: 0..1
    int half = w & 1;             // which edge-chunk parity this wave owns
    int dstv = blockIdx.x * 2 + dl;
    int lane = threadIdx.x & 63;
    floatx4 hd = unpack4(*(const uint2*)(ft + dstv * 256 + lane * 4));
    int deg  = min(cnt[dstv], BCAP);
    int base = dstv * BCAP;
    float l = 0.f;
    floatx4 acc = {0.f, 0.f, 0.f, 0.f};
    for (int i0 = half * 4; i0 < deg; i0 += 8) {
        if (i0 + 4 <= deg) {
            int sn0 = bucket[base + i0],     sn1 = bucket[base + i0 + 1];
            int sn2 = bucket[base + i0 + 2], sn3 = bucket[base + i0 + 3];
            uint2 r0 = *(const uint2*)(ft + sn0 * 256 + lane * 4);
            uint2 r1 = *(const uint2*)(ft + sn1 * 256 + lane * 4);
            uint2 r2 = *(const uint2*)(ft + sn2 * 256 + lane * 4);
            uint2 r3 = *(const uint2*)(ft + sn3 * 256 + lane * 4);
            floatx4 h0 = unpack4(r0), h1 = unpack4(r1), h2 = unpack4(r2), h3 = unpack4(r3);
            float p0 = h0.x * hd.x + h0.y * hd.y + h0.z * hd.z + h0.w * hd.w;
            float p1 = h1.x * hd.x + h1.y * hd.y + h1.z * hd.z + h1.w * hd.w;
            float p2 = h2.x * hd.x + h2.y * hd.y + h2.z * hd.z + h2.w * hd.w;
            float p3 = h3.x * hd.x + h3.y * hd.y + h3.z * hd.z + h3.w * hd.w;
            p0 += __shfl_xor(p0, 1); p1 += __shfl_xor(p1, 1); p2 += __shfl_xor(p2, 1); p3 += __shfl_xor(p3, 1);
            p0 += __shfl_xor(p0, 2); p1 += __shfl_xor(p1, 2); p2 += __shfl_xor(p2, 2); p3 += __shfl_xor(p3, 2);
            p0 += __shfl_xor(p0, 4); p1 += __shfl_xor(p1, 4); p2 += __shfl_xor(p2, 4); p3 += __shfl_xor(p3, 4);
            p0 += __shfl_xor(p0, 8); p1 += __shfl_xor(p1, 8); p2 += __shfl_xor(p2, 8); p3 += __shfl_xor(p3, 8);
            float w0 = __expf(p0 * 0.125f);
            float w1 = __expf(p1 * 0.125f);
            float w2 = __expf(p2 * 0.125f);
            float w3 = __expf(p3 * 0.125f);
            l += (w0 + w1) + (w2 + w3);
            acc.x += w0 * h0.x + w1 * h1.x + w2 * h2.x + w3 * h3.x;
            acc.y += w0 * h0.y + w1 * h1.y + w2 * h2.y + w3 * h3.y;
            acc.z += w0 * h0.z + w1 * h1.z + w2 * h2.z + w3 * h3.z;
            acc.w += w0 * h0.w + w1 * h1.w + w2 * h2.w + w3 * h3.w;
        } else {
            for (int i = i0; i < deg; ++i) {
                int sn = bucket[base + i];
                floatx4 hs = unpack4(*(const uint2*)(ft + sn * 256 + lane * 4));
                float p = hs.x * hd.x + hs.y * hd.y + hs.z * hd.z + hs.w * hd.w;
                p += __shfl_xor(p, 1); p += __shfl_xor(p, 2);
                p += __shfl_xor(p, 4); p += __shfl_xor(p, 8);
                float wgt = __expf(p * 0.125f);
                l += wgt;
                acc.x += wgt * hs.x; acc.y += wgt * hs.y;
                acc.z += wgt * hs.z; acc.w += wgt * hs.w;
            }
        }
    }
    if (half == 1) {
        s_l[dl][lane]   = l;
        s_acc[dl][lane] = acc;
    }
    __syncthreads();
    if (half == 0) {
        l += s_l[dl][lane];
        floatx4 a2 = s_acc[dl][lane];
        acc.x += a2.x; acc.y += a2.y; acc.z += a2.z; acc.w += a2.w;
        float inv = (l > 0.f) ? 1.f / l : 0.f;
        uint2 o;
        o.x = pack2(fmaxf(acc.x * inv, 0.f), fmaxf(acc.y * inv, 0.f));
        o.y = pack2(fmaxf(acc.z * inv, 0.f), fmaxf(acc.w * inv, 0.f));
        *(uint2*)(out + dstv * 256 + lane * 4) = o;
    }
}

// ---------- GEMM2 (MFMA, proven): ft2[M,64] = x1[M,256] @ W2 ----------
__global__ __launch_bounds__(256) void gemm2_kernel(const unsigned short* __restrict__ A,
                                                    const unsigned short* __restrict__ Bt,
                                                    unsigned short* __restrict__ C, int M) {
    int wave = threadIdx.x >> 6;
    int lane = threadIdx.x & 63;
    int q = lane >> 4, r = lane & 15;
    int m0 = blockIdx.x * 256 + wave * 64;
    floatx4 acc[4][4] = {};
#pragma unroll
    for (int kk = 0; kk < 8; ++kk) {
        bf16x8 bfrag[4], afrag[4];
#pragma unroll
        for (int ni = 0; ni < 4; ++ni)
            bfrag[ni] = *(const bf16x8*)(Bt + (ni * 16 + r) * 256 + kk * 32 + q * 8);
#pragma unroll
        for (int mi = 0; mi < 4; ++mi) {
            int row = m0 + mi * 16 + r;
            bf16x8 a = {};
            if (row < M) a = *(const bf16x8*)(A + row * 256 + kk * 32 + q * 8);
            afrag[mi] = a;
        }
#pragma unroll
        for (int mi = 0; mi < 4; ++mi)
#pragma unroll
            for (int ni = 0; ni < 4; ++ni)
                acc[mi][ni] = __builtin_amdgcn_mfma_f32_16x16x32_bf16(afrag[mi], bfrag[ni], acc[mi][ni], 0, 0, 0);
    }
#pragma unroll
    for (int mi = 0; mi < 4; ++mi)
#pragma unroll
        for (int rr = 0; rr < 4; ++rr) {
            int row = m0 + mi * 16 + q * 4 + rr;
            if (row < M) {
#pragma unroll
                for (int ni = 0; ni < 4; ++ni)
                    C[row * 64 + ni * 16 + r] = bf16bits(acc[mi][ni][rr]);
            }
        }
}

// ---------- attention H=1 (proven structure, bucket-indexed): wave=dst, 4 groups, unroll-2 ----------
__global__ __launch_bounds__(256) void attn_h1_kernel(const unsigned short* __restrict__ ft,
                                                      const int* __restrict__ cnt,
                                                      const int* __restrict__ bucket,
                                                      float* __restrict__ out) {
    int dstv = blockIdx.x * 4 + (threadIdx.x >> 6);
    int lane = threadIdx.x & 63;
    int g = lane >> 4, s = lane & 15;
    int hbase = s * 4;
    floatx4 hd = unpack4(*(const uint2*)(ft + dstv * 64 + hbase));
    int deg  = min(cnt[dstv], BCAP);
    int base = dstv * BCAP;
    float l = 0.f;
    floatx4 acc = {0.f, 0.f, 0.f, 0.f};
    int i0 = 0;
    for (; i0 + 8 <= deg; i0 += 8) {
        int ia = i0 + g, ib = i0 + 4 + g;
        int sa = bucket[base + ia], sb = bucket[base + ib];
        uint2 ra = *(const uint2*)(ft + sa * 64 + hbase);
        uint2 rb = *(const uint2*)(ft + sb * 64 + hbase);
        floatx4 ha = unpack4(ra), hb = unpack4(rb);
        float pa = ha.x * hd.x + ha.y * hd.y + ha.z * hd.z + ha.w * hd.w;
        float pb = hb.x * hd.x + hb.y * hd.y + hb.z * hd.z + hb.w * hd.w;
        pa += __shfl_xor(pa, 1); pb += __shfl_xor(pb, 1);
        pa += __shfl_xor(pa, 2); pb += __shfl_xor(pb, 2);
        pa += __shfl_xor(pa, 4); pb += __shfl_xor(pb, 4);
        pa += __shfl_xor(pa, 8); pb += __shfl_xor(pb, 8);
        float wa = __expf(pa * 0.125f);
        float wb = __expf(pb * 0.125f);
        l += wa + wb;
        acc.x += wa * ha.x + wb * hb.x;
        acc.y += wa * ha.y + wb * hb.y;
        acc.z += wa * ha.z + wb * hb.z;
        acc.w += wa * ha.w + wb * hb.w;
    }
    for (; i0 < deg; i0 += 4) {
        int i = i0 + g;
        bool valid = (i < deg);
        int sn = valid ? bucket[base + i] : 0;
        floatx4 hs = unpack4(*(const uint2*)(ft + sn * 64 + hbase));
        float p = hs.x * hd.x + hs.y * hd.y + hs.z * hd.z + hs.w * hd.w;
        p += __shfl_xor(p, 1); p += __shfl_xor(p, 2);
        p += __shfl_xor(p, 4); p += __shfl_xor(p, 8);
        float wgt = valid ? __expf(p * 0.125f) : 0.f;
        l += wgt;
        acc.x += wgt * hs.x; acc.y += wgt * hs.y;
        acc.z += wgt * hs.z; acc.w += wgt * hs.w;
    }
    l += __shfl_xor(l, 16); l += __shfl_xor(l, 32);
    acc.x += __shfl_xor(acc.x, 16); acc.x += __shfl_xor(acc.x, 32);
    acc.y += __shfl_xor(acc.y, 16); acc.y += __shfl_xor(acc.y, 32);
    acc.z += __shfl_xor(acc.z, 16); acc.z += __shfl_xor(acc.z, 32);
    acc.w += __shfl_xor(acc.w, 16); acc.w += __shfl_xor(acc.w, 32);
    float inv = (l > 0.f) ? 1.f / l : 0.f;
    if (g == 0) {
        floatx4 o = {fmaxf(acc.x * inv, 0.f), fmaxf(acc.y * inv, 0.f),
                     fmaxf(acc.z * inv, 0.f), fmaxf(acc.w * inv, 0.f)};
        *(floatx4*)(out + dstv * 64 + hbase) = o;
    }
}

// ---------- fused mean-pool + classifier (proven): 1 block / graph ----------
__global__ __launch_bounds__(256) void poolclass_kernel(const float* __restrict__ x,
                                                        const int* __restrict__ gid,
                                                        const float* __restrict__ Wc,
                                                        const float* __restrict__ bc,
                                                        void* out, const int* flag) {
    __shared__ int s_lo, s_hi;
    __shared__ float part[4][64];
    int g = blockIdx.x;
    int tid = threadIdx.x;
    if (tid == 0) {
        int lo = 0, hi = N_NODES;
        while (lo < hi) { int m = (lo + hi) >> 1; if (gid[m] < g) lo = m + 1; else hi = m; }
        s_lo = lo;
        int lo2 = lo, hi2 = N_NODES;
        while (lo2 < hi2) { int m = (lo2 + hi2) >> 1; if (gid[m] < g + 1) lo2 = m + 1; else hi2 = m; }
        s_hi = lo2;
    }
    __syncthreads();
    int lo = s_lo, hi = s_hi;
    int d = tid & 63, w = tid >> 6;
    float sum = 0.f;
    for (int n = lo + w; n < hi; n += 4) sum += x[n * 64 + d];
    part[w][d] = sum;
    __syncthreads();
    if (w == 0) {
        float tot = part[0][d] + part[1][d] + part[2][d] + part[3][d];
        int cntg = hi - lo;
        float mean = (cntg > 0) ? tot / (float)cntg : 0.f;
        for (int cls = 0; cls < N_CLASSES; ++cls) {
            float p = mean * Wc[d * N_CLASSES + cls];
#pragma unroll
            for (int o = 1; o < 64; o <<= 1) p += __shfl_xor(p, o);
            if (d == 0) {
                float r = p + bc[cls];
                if (*flag) ((__hip_bfloat16*)out)[g * N_CLASSES + cls] = __float2bfloat16(r);
                else       ((float*)out)[g * N_CLASSES + cls] = r;
            }
        }
    }
}

static inline size_t align256(size_t x) { return (x + 255) & ~size_t(255); }

extern "C" void kernel_launch(void* const* d_in, const int* in_sizes, int n_in,
                              void* d_out, int out_size, void* d_ws, size_t ws_size,
                              hipStream_t stream) {
    const void* h_raw  = d_in[0];
    const int*  src    = (const int*)d_in[1];
    const int*  dst    = (const int*)d_in[2];
    const int*  gid    = (const int*)d_in[3];
    const void* W1_raw = d_in[4];
    const void* W2_raw = d_in[5];
    const void* Wc_raw = d_in[6];
    const void* bc_raw = d_in[7];

    // ---- workspace layout ----
    char* w = (char*)d_ws;
    int*  flag     = (int*)w;                      w += 256;
    int*  cnt      = (int*)w;                      w += align256(N_NODES * 4);
    int*  bucket   = (int*)w;                      w += align256((size_t)N_NODES * BCAP * 4);  // 10.24MB
    unsigned short* W1t = (unsigned short*)w;      w += align256(256 * 128 * 2);
    unsigned short* W2t = (unsigned short*)w;      w += align256(64 * 256 * 2);
    float* Wcf     = (float*)w;                    w += align256(HID * N_CLASSES * 4);
    float* bcf     = (float*)w;                    w += 256;
    unsigned short* h_b  = (unsigned short*)w;     w += align256((size_t)N_NODES * IN_DIM * 2);
    unsigned short* ft1  = (unsigned short*)w;     w += align256((size_t)N_NODES * 256 * 2);
    unsigned short* x1   = (unsigned short*)w;     w += align256((size_t)N_NODES * 256 * 2);
    unsigned short* ft2  = (unsigned short*)w;     w += align256((size_t)N_NODES * HID * 2);
    float* x2      = (float*)w;                    w += align256((size_t)N_NODES * HID * 4);

    // 1) init: detect (block 0) + zero cnt
    hipLaunchKernelGGL(init_kernel, dim3(1 + (N_NODES + 255) / 256), dim3(256), 0, stream,
                       (const unsigned int*)h_raw, 4096, flag,
                       (unsigned int*)cnt, N_NODES);

    // 2) fused prep: convW (195) + convH-if-f32 (640) + bucket-fill (1250)
    hipLaunchKernelGGL(prep_kernel, dim3(195 + 640 + 1250), dim3(256), 0, stream,
                       W1_raw, W2_raw, Wc_raw, bc_raw, W1t, W2t, Wcf, bcf,
                       h_raw, h_b, src, dst, cnt, bucket, flag);

    // 3) layer 1 GEMM (MFMA)
    hipLaunchKernelGGL(gemm1_kernel, dim3((N_NODES + 63) / 64), dim3(256), 0, stream,
                       h_raw, h_b, W1t, ft1, N_NODES, flag);

    // 4) attention layer 1 -> x1 (bf16)  [2 waves/dst]
    hipLaunchKernelGGL(attn_h4_kernel, dim3(N_NODES / 2), dim3(256), 0, stream,
                       ft1, cnt, bucket, x1);

    // 5) layer 2 GEMM (MFMA)
    hipLaunchKernelGGL(gemm2_kernel, dim3((N_NODES + 255) / 256), dim3(256), 0, stream,
                       x1, W2t, ft2, N_NODES);

    // 6) attention layer 2 -> x2 (f32)
    hipLaunchKernelGGL(attn_h1_kernel, dim3(N_NODES / 4), dim3(256), 0, stream,
                       ft2, cnt, bucket, x2);

    // 7) fused mean-pool + classifier -> d_out
    hipLaunchKernelGGL(poolclass_kernel, dim3(NUM_GRAPHS), dim3(256), 0, stream,
                       x2, gid, Wcf, bcf, d_out, flag);
}